// Round 1
// baseline (227.090 us; speedup 1.0000x reference)
//
#include <hip/hip_runtime.h>
#include <math.h>

#define IMG_H 512
#define IMG_W 512
#define PSIZE 512
#define NIMG 16
#define NBOX 16
#define RED_BLOCKS 256

// ---------------------------------------------------------------------------
// Block-wide reduction of 6 floats (sum/sumsq per channel). Deterministic tree.
// ---------------------------------------------------------------------------
template<int NWAVES>
__device__ __forceinline__ void block_reduce6(float v[6]) {
    __shared__ float lds[NWAVES][6];
    const int lane = threadIdx.x & 63;
    const int wave = threadIdx.x >> 6;
    __syncthreads();  // guard LDS reuse across successive invocations
#pragma unroll
    for (int k = 0; k < 6; ++k) {
#pragma unroll
        for (int off = 32; off > 0; off >>= 1)
            v[k] += __shfl_down(v[k], off, 64);
    }
    if (lane == 0) {
#pragma unroll
        for (int k = 0; k < 6; ++k) lds[wave][k] = v[k];
    }
    __syncthreads();
    if (wave == 0) {
#pragma unroll
        for (int k = 0; k < 6; ++k) {
            float x = (lane < NWAVES) ? lds[lane][k] : 0.0f;
#pragma unroll
            for (int off = 32; off > 0; off >>= 1)
                x += __shfl_down(x, off, 64);
            if (lane == 0) lds[0][k] = x;
        }
    }
    __syncthreads();
#pragma unroll
    for (int k = 0; k < 6; ++k) v[k] = lds[0][k];
}

// ---------------------------------------------------------------------------
// Stage 1: per-block partial sums/sumsqs of the patch (per channel).
// ws layout: ws[0..2]=p_mean, ws[3..5]=p_std, ws[6 .. 6+RED_BLOCKS*6)=partials
// ---------------------------------------------------------------------------
__global__ void patch_stats_partial(const float* __restrict__ patch,
                                    float* __restrict__ ws) {
    const int tid = blockIdx.x * blockDim.x + threadIdx.x;
    const int stride = gridDim.x * blockDim.x;
    float v[6] = {0.f, 0.f, 0.f, 0.f, 0.f, 0.f};
    for (int p = tid; p < PSIZE * PSIZE; p += stride) {
        const float* q = patch + 3 * p;
        float a = q[0], b = q[1], c = q[2];
        v[0] += a; v[1] += b; v[2] += c;
        v[3] += a * a; v[4] += b * b; v[5] += c * c;
    }
    block_reduce6<4>(v);
    if (threadIdx.x == 0) {
        float* o = ws + 6 + blockIdx.x * 6;
#pragma unroll
        for (int k = 0; k < 6; ++k) o[k] = v[k];
    }
}

// Stage 2: reduce RED_BLOCKS partials -> p_mean, p_std (population std + 1e-6)
__global__ void patch_stats_final(float* __restrict__ ws) {
    float v[6];
    const float* p = ws + 6 + threadIdx.x * 6;  // blockDim.x == RED_BLOCKS
#pragma unroll
    for (int k = 0; k < 6; ++k) v[k] = p[k];
    block_reduce6<4>(v);
    if (threadIdx.x == 0) {
        const float n = (float)(PSIZE * PSIZE);
#pragma unroll
        for (int c = 0; c < 3; ++c) {
            float m = v[c] / n;
            float var = v[3 + c] / n - m * m;
            ws[c] = m;
            ws[3 + c] = sqrtf(fmaxf(var, 0.f)) + 1e-6f;
        }
    }
}

// ---------------------------------------------------------------------------
// Main kernel: one block per image, serial over the 16 patches (the reference
// scan is serial: bg stats use the already-patched image).
// ---------------------------------------------------------------------------
__launch_bounds__(1024)
__global__ void patcher(const float* __restrict__ boxes,
                        const float* __restrict__ patch,
                        const float* __restrict__ stats,
                        float* __restrict__ out) {
    const int b = blockIdx.x;
    const int tid = threadIdx.x;

    __shared__ int sy0[NBOX], sx0[NBOX], sph[NBOX], spw[NBOX], svalid[NBOX];
    __shared__ float s_pmean[3], s_pstd[3];
    __shared__ float s_bg[6];  // bg_mean[3], scale[3] = bg_std/p_std

    if (tid < NBOX) {
        const float* bx = boxes + (b * NBOX + tid) * 4;
        float ymin = bx[0], xmin = bx[1], ymax = bx[2], xmax = bx[3];
        float h = ymax - ymin, w = xmax - xmin;
        float pw = h * 0.3f;        // SCALE
        float ph = 1.0f * pw;       // ASPECT * pw
        float oy = ymin + h * 0.5f;
        float ox = xmin + w * 0.5f;
        float yp = fmaxf(oy - ph * 0.5f, 0.0f);
        float xp = fmaxf(ox - pw * 0.5f, 0.0f);
        if (yp + ph > (float)IMG_H) yp = (float)IMG_H - ph;
        if (xp + pw > (float)IMG_W) xp = (float)IMG_W - pw;
        sy0[tid] = (int)yp;         // tf.cast truncation
        sx0[tid] = (int)xp;
        sph[tid] = (int)ph;
        spw[tid] = (int)pw;
        svalid[tid] = (ph > 60.0f) ? 1 : 0;   // MIN_PATCH_H on the float ph
    }
    if (tid < 3) {
        s_pmean[tid] = stats[tid];
        s_pstd[tid] = stats[3 + tid];
    }
    __syncthreads();

    float* img = out + (size_t)b * IMG_H * IMG_W * 3;

    for (int i = 0; i < NBOX; ++i) {
        if (!svalid[i]) continue;   // uniform branch (LDS value)
        const int y0 = sy0[i], x0 = sx0[i], ph = sph[i], pw = spw[i];
        const int npix = ph * pw;

        // ---- pass 1: background mean/std over the rect (current image) ----
        float v[6] = {0.f, 0.f, 0.f, 0.f, 0.f, 0.f};
        for (int t = tid; t < npix; t += 1024) {
            int y = y0 + t / pw;
            int x = x0 + t % pw;
            const float* p = img + (y * IMG_W + x) * 3;
            float a = p[0], bb = p[1], c = p[2];
            v[0] += a; v[1] += bb; v[2] += c;
            v[3] += a * a; v[4] += bb * bb; v[5] += c * c;
        }
        block_reduce6<16>(v);
        if (tid == 0) {
            float cnt = fmaxf((float)npix, 1.0f);
#pragma unroll
            for (int c = 0; c < 3; ++c) {
                float m = v[c] / cnt;
                float var = v[3 + c] / cnt - m * m;
                float sd = sqrtf(fmaxf(var, 0.f)) + 1e-6f;
                s_bg[c] = m;
                s_bg[3 + c] = sd / s_pstd[c];
            }
        }
        __syncthreads();

        // ---- pass 2: bilinear-sample patch, affine match, write rect ----
        const float phf = fmaxf((float)ph, 1.0f);
        const float pwf = fmaxf((float)pw, 1.0f);
        const float bm0 = s_bg[0], bm1 = s_bg[1], bm2 = s_bg[2];
        const float sc0 = s_bg[3], sc1 = s_bg[4], sc2 = s_bg[5];
        const float pm0 = s_pmean[0], pm1 = s_pmean[1], pm2 = s_pmean[2];

        for (int t = tid; t < npix; t += 1024) {
            int y = y0 + t / pw;
            int x = x0 + t % pw;
            float sy = ((float)(y - y0) + 0.5f) * 512.0f / phf - 0.5f;
            sy = fminf(fmaxf(sy, 0.0f), 511.0f);
            float sx = ((float)(x - x0) + 0.5f) * 512.0f / pwf - 0.5f;
            sx = fminf(fmaxf(sx, 0.0f), 511.0f);
            int iy0 = (int)floorf(sy);
            int iy1 = min(iy0 + 1, PSIZE - 1);
            int ix0 = (int)floorf(sx);
            int ix1 = min(ix0 + 1, PSIZE - 1);
            float wy = sy - (float)iy0;
            float wx = sx - (float)ix0;
            const float* p00 = patch + (iy0 * PSIZE + ix0) * 3;
            const float* p01 = patch + (iy0 * PSIZE + ix1) * 3;
            const float* p10 = patch + (iy1 * PSIZE + ix0) * 3;
            const float* p11 = patch + (iy1 * PSIZE + ix1) * 3;
            float* o = img + (y * IMG_W + x) * 3;

            float top0 = (1.f - wx) * p00[0] + wx * p01[0];
            float bot0 = (1.f - wx) * p10[0] + wx * p11[0];
            float s0 = (1.f - wy) * top0 + wy * bot0;
            float top1 = (1.f - wx) * p00[1] + wx * p01[1];
            float bot1 = (1.f - wx) * p10[1] + wx * p11[1];
            float s1 = (1.f - wy) * top1 + wy * bot1;
            float top2 = (1.f - wx) * p00[2] + wx * p01[2];
            float bot2 = (1.f - wx) * p10[2] + wx * p11[2];
            float s2 = (1.f - wy) * top2 + wy * bot2;

            o[0] = (s0 - pm0) * sc0 + bm0;
            o[1] = (s1 - pm1) * sc1 + bm1;
            o[2] = (s2 - pm2) * sc2 + bm2;
        }
        __syncthreads();  // writes visible before next patch's pass 1
    }
}

extern "C" void kernel_launch(void* const* d_in, const int* in_sizes, int n_in,
                              void* d_out, int out_size, void* d_ws, size_t ws_size,
                              hipStream_t stream) {
    const float* images = (const float*)d_in[0];  // [16,512,512,3]
    const float* boxes  = (const float*)d_in[1];  // [16,16,4]
    const float* patch  = (const float*)d_in[2];  // [512,512,3]
    float* out = (float*)d_out;                   // [16,512,512,3]
    float* ws  = (float*)d_ws;

    // 1) out <- images (patches then applied in place)
    hipMemcpyAsync(out, images,
                   (size_t)NIMG * IMG_H * IMG_W * 3 * sizeof(float),
                   hipMemcpyDeviceToDevice, stream);

    // 2) patch mean/std (deterministic two-stage reduction)
    patch_stats_partial<<<RED_BLOCKS, 256, 0, stream>>>(patch, ws);
    patch_stats_final<<<1, RED_BLOCKS, 0, stream>>>(ws);

    // 3) serial per-image patcher, one block per image
    patcher<<<NIMG, 1024, 0, stream>>>(boxes, patch, ws, out);
}

// Round 2
// 130.525 us; speedup vs baseline: 1.7398x; 1.7398x over previous
//
#include <hip/hip_runtime.h>
#include <math.h>

#define IMG_H 512
#define IMG_W 512
#define PSIZE 512
#define NIMG 16
#define NBOX 16
#define RED_BLOCKS 256

// workspace layout (floats)
#define WS_PMEAN 0                               // 3
#define WS_PSTD  3                               // 3
#define WS_PART  6                               // RED_BLOCKS*6
#define WS_PAIR  (6 + RED_BLOCKS * 6)            // [b][i][j_idx 0..16][8]: cnt,S1[3],S2[3]
#define WS_COEF  (WS_PAIR + NIMG * NBOX * 17 * 8)// [b][i][8]: scale[3], off[3]

struct BoxGeo { int y0, x0, ph, pw, valid; };

__device__ __forceinline__ BoxGeo make_geo(const float* bx) {
    float ymin = bx[0], xmin = bx[1], ymax = bx[2], xmax = bx[3];
    float h = ymax - ymin, w = xmax - xmin;
    float pwf = h * 0.3f;            // SCALE
    float phf = 1.0f * pwf;          // ASPECT * pw
    float oy = ymin + h * 0.5f;
    float ox = xmin + w * 0.5f;
    float yp = fmaxf(oy - phf * 0.5f, 0.0f);
    float xp = fmaxf(ox - pwf * 0.5f, 0.0f);
    if (yp + phf > (float)IMG_H) yp = (float)IMG_H - phf;
    if (xp + pwf > (float)IMG_W) xp = (float)IMG_W - pwf;
    BoxGeo g;
    g.y0 = (int)yp; g.x0 = (int)xp;   // tf.cast truncation
    g.ph = (int)phf; g.pw = (int)pwf;
    g.valid = (phf > 60.0f) ? 1 : 0;  // MIN_PATCH_H tested on float ph
    return g;
}

// bilinear sample of patch (tf half-pixel centers) at rel position in a
// (phf x pwf)-sized resize grid
__device__ __forceinline__ void bsample(const float* __restrict__ patch,
                                        int relY, int relX, float phf, float pwf,
                                        float s[3]) {
    float sy = ((float)relY + 0.5f) * (float)PSIZE / phf - 0.5f;
    sy = fminf(fmaxf(sy, 0.0f), (float)(PSIZE - 1));
    float sx = ((float)relX + 0.5f) * (float)PSIZE / pwf - 0.5f;
    sx = fminf(fmaxf(sx, 0.0f), (float)(PSIZE - 1));
    int y0 = (int)floorf(sy);
    int y1 = min(y0 + 1, PSIZE - 1);
    int x0 = (int)floorf(sx);
    int x1 = min(x0 + 1, PSIZE - 1);
    float wy = sy - (float)y0;
    float wx = sx - (float)x0;
    const float* p00 = patch + (y0 * PSIZE + x0) * 3;
    const float* p01 = patch + (y0 * PSIZE + x1) * 3;
    const float* p10 = patch + (y1 * PSIZE + x0) * 3;
    const float* p11 = patch + (y1 * PSIZE + x1) * 3;
#pragma unroll
    for (int c = 0; c < 3; ++c) {
        float top = (1.f - wx) * p00[c] + wx * p01[c];
        float bot = (1.f - wx) * p10[c] + wx * p11[c];
        s[c] = (1.f - wy) * top + wy * bot;
    }
}

// deterministic block tree-reduction of N floats
template<int N, int NWAVES>
__device__ __forceinline__ void block_reduceN(float v[N]) {
    __shared__ float lds[NWAVES][N];
    const int lane = threadIdx.x & 63;
    const int wave = threadIdx.x >> 6;
    __syncthreads();
#pragma unroll
    for (int k = 0; k < N; ++k) {
#pragma unroll
        for (int off = 32; off > 0; off >>= 1)
            v[k] += __shfl_down(v[k], off, 64);
    }
    if (lane == 0) {
#pragma unroll
        for (int k = 0; k < N; ++k) lds[wave][k] = v[k];
    }
    __syncthreads();
    if (wave == 0) {
#pragma unroll
        for (int k = 0; k < N; ++k) {
            float x = (lane < NWAVES) ? lds[lane][k] : 0.0f;
#pragma unroll
            for (int off = 32; off > 0; off >>= 1)
                x += __shfl_down(x, off, 64);
            if (lane == 0) lds[0][k] = x;
        }
    }
    __syncthreads();
#pragma unroll
    for (int k = 0; k < N; ++k) v[k] = lds[0][k];
}

// ---------------------------------------------------------------------------
// patch mean/std (two-stage deterministic reduction)
// ---------------------------------------------------------------------------
__global__ void patch_stats_partial(const float* __restrict__ patch,
                                    float* __restrict__ ws) {
    const int tid = blockIdx.x * blockDim.x + threadIdx.x;
    const int stride = gridDim.x * blockDim.x;
    float v[6] = {0.f, 0.f, 0.f, 0.f, 0.f, 0.f};
    for (int p = tid; p < PSIZE * PSIZE; p += stride) {
        const float* q = patch + 3 * p;
        float a = q[0], b = q[1], c = q[2];
        v[0] += a; v[1] += b; v[2] += c;
        v[3] += a * a; v[4] += b * b; v[5] += c * c;
    }
    block_reduceN<6, 4>(v);
    if (threadIdx.x == 0) {
        float* o = ws + WS_PART + blockIdx.x * 6;
#pragma unroll
        for (int k = 0; k < 6; ++k) o[k] = v[k];
    }
}

__global__ void patch_stats_final(float* __restrict__ ws) {
    float v[6];
    const float* p = ws + WS_PART + threadIdx.x * 6;
#pragma unroll
    for (int k = 0; k < 6; ++k) v[k] = p[k];
    block_reduceN<6, 4>(v);
    if (threadIdx.x == 0) {
        const float n = (float)(PSIZE * PSIZE);
#pragma unroll
        for (int c = 0; c < 3; ++c) {
            float m = v[c] / n;
            float var = v[3 + c] / n - m * m;
            ws[WS_PMEAN + c] = m;
            ws[WS_PSTD + c] = sqrtf(fmaxf(var, 0.f)) + 1e-6f;
        }
    }
}

// ---------------------------------------------------------------------------
// Kernel A: geometric pair sums. block = (b*16+i, j_idx). j = j_idx-1 (-1 = orig).
// Over pixels p of rect_i whose LAST valid coverer among patches < i is j:
//   cnt, per-channel { Σ sample_j(p) , Σ sample_j(p)^2 }   (j>=0: bilinear of patch)
//   for j == -1: sums of the original image pixels.
// ---------------------------------------------------------------------------
__launch_bounds__(256)
__global__ void pair_sums(const float* __restrict__ images,
                          const float* __restrict__ boxes,
                          const float* __restrict__ patch,
                          float* __restrict__ ws) {
    const int bi = blockIdx.x;          // b*16 + i
    const int j_idx = blockIdx.y;       // 0..16
    const int b = bi >> 4, i = bi & 15;
    if (j_idx > i) return;

    __shared__ BoxGeo geo[NBOX];
    if (threadIdx.x < NBOX)
        geo[threadIdx.x] = make_geo(boxes + (b * NBOX + threadIdx.x) * 4);
    __syncthreads();

    const BoxGeo gi = geo[i];
    if (!gi.valid) return;              // uniform

    const int j = j_idx - 1;
    const int npix = gi.ph * gi.pw;
    const float* img = images + (size_t)b * IMG_H * IMG_W * 3;

    int jy0 = 0, jx0 = 0; float jphf = 1.f, jpwf = 1.f; int jvalid = 0;
    if (j >= 0) {
        BoxGeo gj = geo[j];
        jy0 = gj.y0; jx0 = gj.x0;
        jphf = (float)gj.ph; jpwf = (float)gj.pw;
        jvalid = gj.valid;
        if (!jvalid) {  // invalid patch never covers: all sums zero
            if (threadIdx.x == 0) {
                float* o = ws + WS_PAIR + ((size_t)(b * NBOX + i) * 17 + j_idx) * 8;
#pragma unroll
                for (int k = 0; k < 7; ++k) o[k] = 0.f;
            }
            return;
        }
    }

    float v[7] = {0.f, 0.f, 0.f, 0.f, 0.f, 0.f, 0.f};
    for (int t = threadIdx.x; t < npix; t += 256) {
        const int y = gi.y0 + t / gi.pw;
        const int x = gi.x0 + t % gi.pw;
        bool inc;
        if (j >= 0)
            inc = (y >= jy0) && (y < jy0 + (int)jphf) && (x >= jx0) && (x < jx0 + (int)jpwf);
        else
            inc = true;
        if (inc) {
            for (int k = j + 1; k < i; ++k) {
                BoxGeo gk = geo[k];
                if (gk.valid && y >= gk.y0 && y < gk.y0 + gk.ph &&
                    x >= gk.x0 && x < gk.x0 + gk.pw) { inc = false; break; }
            }
        }
        if (inc) {
            float s[3];
            if (j >= 0) {
                bsample(patch, y - jy0, x - jx0, jphf, jpwf, s);
            } else {
                const float* p = img + ((size_t)y * IMG_W + x) * 3;
                s[0] = p[0]; s[1] = p[1]; s[2] = p[2];
            }
            v[0] += 1.f;
            v[1] += s[0]; v[2] += s[1]; v[3] += s[2];
            v[4] += s[0] * s[0]; v[5] += s[1] * s[1]; v[6] += s[2] * s[2];
        }
    }
    block_reduceN<7, 4>(v);
    if (threadIdx.x == 0) {
        float* o = ws + WS_PAIR + ((size_t)(b * NBOX + i) * 17 + j_idx) * 8;
#pragma unroll
        for (int k = 0; k < 7; ++k) o[k] = v[k];
    }
}

// ---------------------------------------------------------------------------
// Kernel B: per-image 16-step scalar recurrence -> scale/off per patch.
// One wave per image; lane l holds the coeffs of patch j=l-1 and computes the
// j=l-1 term of the bg sums for each i.
// ---------------------------------------------------------------------------
__global__ void solve_coeffs(const float* __restrict__ boxes,
                             float* __restrict__ ws) {
    const int b = blockIdx.x;
    const int lane = threadIdx.x;       // 64 threads = 1 wave

    BoxGeo g = make_geo(boxes + (b * NBOX + (lane < NBOX ? lane : NBOX - 1)) * 4);
    float pm[3], ps[3];
#pragma unroll
    for (int c = 0; c < 3; ++c) { pm[c] = ws[WS_PMEAN + c]; ps[c] = ws[WS_PSTD + c]; }

    float sc[3] = {0.f, 0.f, 0.f}, of[3] = {0.f, 0.f, 0.f}; // coeffs of patch lane-1

    for (int i = 0; i < NBOX; ++i) {
        const int valid_i = __shfl(g.valid, i, 64);
        if (!valid_i) continue;          // uniform

        float cnt = 0.f, s1[3] = {0.f,0.f,0.f}, s2[3] = {0.f,0.f,0.f};
        if (lane <= i) {
            const float* p = ws + WS_PAIR + ((size_t)(b * NBOX + i) * 17 + lane) * 8;
            cnt = p[0];
            s1[0] = p[1]; s1[1] = p[2]; s1[2] = p[3];
            s2[0] = p[4]; s2[1] = p[5]; s2[2] = p[6];
        }
        float ts[3], tq[3];
#pragma unroll
        for (int c = 0; c < 3; ++c) {
            if (lane == 0) { ts[c] = s1[c]; tq[c] = s2[c]; }
            else {
                ts[c] = sc[c] * s1[c] + of[c] * cnt;
                tq[c] = sc[c] * sc[c] * s2[c] + 2.f * sc[c] * of[c] * s1[c]
                      + of[c] * of[c] * cnt;
            }
        }
        // reduce lanes 0..16 (lanes 17..31 hold zeros), width-32 tree
#pragma unroll
        for (int c = 0; c < 3; ++c) {
#pragma unroll
            for (int off = 16; off > 0; off >>= 1) {
                ts[c] += __shfl_down(ts[c], off, 32);
                tq[c] += __shfl_down(tq[c], off, 32);
            }
        }
        const int phi = __shfl(g.ph, i, 64);
        const int pwi = __shfl(g.pw, i, 64);
        const float cntf = fmaxf((float)(phi * pwi), 1.0f);
        float nsc[3] = {0.f,0.f,0.f}, nof[3] = {0.f,0.f,0.f};
        if (lane == 0) {
#pragma unroll
            for (int c = 0; c < 3; ++c) {
                float mean = ts[c] / cntf;
                float var = tq[c] / cntf - mean * mean;
                float sd = sqrtf(fmaxf(var, 0.f)) + 1e-6f;
                nsc[c] = sd / ps[c];
                nof[c] = mean - pm[c] * nsc[c];
            }
        }
#pragma unroll
        for (int c = 0; c < 3; ++c) {
            float bs = __shfl(nsc[c], 0, 64);
            float bo = __shfl(nof[c], 0, 64);
            if (lane == i + 1) { sc[c] = bs; of[c] = bo; }
            if (lane == 0) {
                ws[WS_COEF + (size_t)(b * NBOX + i) * 8 + c] = bs;
                ws[WS_COEF + (size_t)(b * NBOX + i) * 8 + 3 + c] = bo;
            }
        }
    }
}

// ---------------------------------------------------------------------------
// Kernel C: render. Every output pixel = orig, or affine(bilinear sample) of
// its LAST valid covering patch.
// ---------------------------------------------------------------------------
__launch_bounds__(256)
__global__ void render(const float* __restrict__ images,
                       const float* __restrict__ boxes,
                       const float* __restrict__ patch,
                       const float* __restrict__ ws,
                       float* __restrict__ out) {
    const int b = blockIdx.y;
    __shared__ BoxGeo geo[NBOX];
    __shared__ float coef[NBOX][6];
    if (threadIdx.x < NBOX)
        geo[threadIdx.x] = make_geo(boxes + (b * NBOX + threadIdx.x) * 4);
    if (threadIdx.x < NBOX * 6) {
        int i = threadIdx.x / 6, c = threadIdx.x % 6;
        coef[i][c] = ws[WS_COEF + (size_t)(b * NBOX + i) * 8 + c];
    }
    __syncthreads();

    const int p = blockIdx.x * 256 + threadIdx.x;   // 0 .. 512*512-1
    const int y = p >> 9, x = p & 511;

    int last = -1;
    for (int j = NBOX - 1; j >= 0; --j) {
        BoxGeo g = geo[j];
        if (g.valid && y >= g.y0 && y < g.y0 + g.ph &&
            x >= g.x0 && x < g.x0 + g.pw) { last = j; break; }
    }

    const size_t base = ((size_t)b * IMG_H * IMG_W + p) * 3;
    float o0, o1, o2;
    if (last < 0) {
        o0 = images[base]; o1 = images[base + 1]; o2 = images[base + 2];
    } else {
        BoxGeo g = geo[last];
        float s[3];
        bsample(patch, y - g.y0, x - g.x0, (float)g.ph, (float)g.pw, s);
        o0 = s[0] * coef[last][0] + coef[last][3];
        o1 = s[1] * coef[last][1] + coef[last][4];
        o2 = s[2] * coef[last][2] + coef[last][5];
    }
    out[base] = o0; out[base + 1] = o1; out[base + 2] = o2;
}

extern "C" void kernel_launch(void* const* d_in, const int* in_sizes, int n_in,
                              void* d_out, int out_size, void* d_ws, size_t ws_size,
                              hipStream_t stream) {
    const float* images = (const float*)d_in[0];  // [16,512,512,3]
    const float* boxes  = (const float*)d_in[1];  // [16,16,4]
    const float* patch  = (const float*)d_in[2];  // [512,512,3]
    float* out = (float*)d_out;                   // [16,512,512,3]
    float* ws  = (float*)d_ws;

    // patch mean/std
    patch_stats_partial<<<RED_BLOCKS, 256, 0, stream>>>(patch, ws);
    patch_stats_final<<<1, RED_BLOCKS, 0, stream>>>(ws);

    // geometric pair sums (parallel over all (image, patch, coverer))
    pair_sums<<<dim3(NIMG * NBOX, 17), 256, 0, stream>>>(images, boxes, patch, ws);

    // tiny serial recurrence per image
    solve_coeffs<<<NIMG, 64, 0, stream>>>(boxes, ws);

    // full-image render
    render<<<dim3(IMG_H * IMG_W / 256, NIMG), 256, 0, stream>>>(images, boxes, patch, ws, out);
}

// Round 5
// 106.033 us; speedup vs baseline: 2.1417x; 1.2310x over previous
//
#include <hip/hip_runtime.h>
#include <math.h>

#define IMG_H 512
#define IMG_W 512
#define PSIZE 512
#define NIMG 16
#define NBOX 16
#define RED_BLOCKS 256
#define ZSPLIT 4

// workspace layout (floats)
#define WS_PMEAN 0                                        // 3
#define WS_PSTD  3                                        // 3
#define WS_PART  6                                        // RED_BLOCKS*6
#define WS_PAIR  (6 + RED_BLOCKS * 6)                     // [b][i][j 0..16][z][8]
#define WS_COEF  (WS_PAIR + NIMG * NBOX * 17 * ZSPLIT * 8)// [b][i][8]

struct BoxGeo { int y0, x0, ph, pw, valid; };

__device__ __forceinline__ BoxGeo make_geo(const float* bx) {
    float ymin = bx[0], xmin = bx[1], ymax = bx[2], xmax = bx[3];
    float h = ymax - ymin, w = xmax - xmin;
    float pwf = h * 0.3f;            // SCALE
    float phf = 1.0f * pwf;          // ASPECT * pw
    float oy = ymin + h * 0.5f;
    float ox = xmin + w * 0.5f;
    float yp = fmaxf(oy - phf * 0.5f, 0.0f);
    float xp = fmaxf(ox - pwf * 0.5f, 0.0f);
    if (yp + phf > (float)IMG_H) yp = (float)IMG_H - phf;
    if (xp + pwf > (float)IMG_W) xp = (float)IMG_W - pwf;
    BoxGeo g;
    g.y0 = (int)yp; g.x0 = (int)xp;   // tf.cast truncation
    g.ph = (int)phf; g.pw = (int)pwf;
    g.valid = (phf > 60.0f) ? 1 : 0;  // MIN_PATCH_H tested on float ph
    return g;
}

__device__ __forceinline__ void bsample(const float* __restrict__ patch,
                                        int relY, int relX, float phf, float pwf,
                                        float s[3]) {
    float sy = ((float)relY + 0.5f) * (float)PSIZE / phf - 0.5f;
    sy = fminf(fmaxf(sy, 0.0f), (float)(PSIZE - 1));
    float sx = ((float)relX + 0.5f) * (float)PSIZE / pwf - 0.5f;
    sx = fminf(fmaxf(sx, 0.0f), (float)(PSIZE - 1));
    int y0 = (int)floorf(sy);
    int y1 = min(y0 + 1, PSIZE - 1);
    int x0 = (int)floorf(sx);
    int x1 = min(x0 + 1, PSIZE - 1);
    float wy = sy - (float)y0;
    float wx = sx - (float)x0;
    const float* p00 = patch + (y0 * PSIZE + x0) * 3;
    const float* p01 = patch + (y0 * PSIZE + x1) * 3;
    const float* p10 = patch + (y1 * PSIZE + x0) * 3;
    const float* p11 = patch + (y1 * PSIZE + x1) * 3;
#pragma unroll
    for (int c = 0; c < 3; ++c) {
        float top = (1.f - wx) * p00[c] + wx * p01[c];
        float bot = (1.f - wx) * p10[c] + wx * p11[c];
        s[c] = (1.f - wy) * top + wy * bot;
    }
}

template<int N, int NWAVES>
__device__ __forceinline__ void block_reduceN(float v[N]) {
    __shared__ float lds[NWAVES][N];
    const int lane = threadIdx.x & 63;
    const int wave = threadIdx.x >> 6;
    __syncthreads();
#pragma unroll
    for (int k = 0; k < N; ++k) {
#pragma unroll
        for (int off = 32; off > 0; off >>= 1)
            v[k] += __shfl_down(v[k], off, 64);
    }
    if (lane == 0) {
#pragma unroll
        for (int k = 0; k < N; ++k) lds[wave][k] = v[k];
    }
    __syncthreads();
    if (wave == 0) {
#pragma unroll
        for (int k = 0; k < N; ++k) {
            float x = (lane < NWAVES) ? lds[lane][k] : 0.0f;
#pragma unroll
            for (int off = 32; off > 0; off >>= 1)
                x += __shfl_down(x, off, 64);
            if (lane == 0) lds[0][k] = x;
        }
    }
    __syncthreads();
#pragma unroll
    for (int k = 0; k < N; ++k) v[k] = lds[0][k];
}

// ---------------------------------------------------------------------------
// patch mean/std — vectorized: thread g loads float4[3g..3g+2] = 4 RGB pixels
// ---------------------------------------------------------------------------
__global__ void patch_stats_partial(const float* __restrict__ patch,
                                    float* __restrict__ ws) {
    const int g = blockIdx.x * 256 + threadIdx.x;   // 0..65535
    const float4* p4 = (const float4*)patch;
    float4 a = p4[3 * g], b = p4[3 * g + 1], c = p4[3 * g + 2];
    // channels rotate: a=(R,G,B,R) b=(G,B,R,G) c=(B,R,G,B)
    float v[6];
    v[0] = a.x + a.w + b.z + c.y;
    v[1] = a.y + b.x + b.w + c.z;
    v[2] = a.z + b.y + c.x + c.w;
    v[3] = a.x*a.x + a.w*a.w + b.z*b.z + c.y*c.y;
    v[4] = a.y*a.y + b.x*b.x + b.w*b.w + c.z*c.z;
    v[5] = a.z*a.z + b.y*b.y + c.x*c.x + c.w*c.w;
    block_reduceN<6, 4>(v);
    if (threadIdx.x == 0) {
        float* o = ws + WS_PART + blockIdx.x * 6;
#pragma unroll
        for (int k = 0; k < 6; ++k) o[k] = v[k];
    }
}

__global__ void patch_stats_final(float* __restrict__ ws) {
    float v[6];
    const float* p = ws + WS_PART + threadIdx.x * 6;
#pragma unroll
    for (int k = 0; k < 6; ++k) v[k] = p[k];
    block_reduceN<6, 4>(v);
    if (threadIdx.x == 0) {
        const float n = (float)(PSIZE * PSIZE);
#pragma unroll
        for (int c = 0; c < 3; ++c) {
            float m = v[c] / n;
            float var = v[3 + c] / n - m * m;
            ws[WS_PMEAN + c] = m;
            ws[WS_PSTD + c] = sqrtf(fmaxf(var, 0.f)) + 1e-6f;
        }
    }
}

// ---------------------------------------------------------------------------
// Kernel A: pair sums over last-coverer regions.
// block = (b*16+i, j_idx 0..16, z). j = j_idx-1 (-1 = original image).
// For j>=0 scan only rect_i ∩ rect_j; z splits the pixel range 4-way.
// ---------------------------------------------------------------------------
__launch_bounds__(256)
__global__ void pair_sums(const float* __restrict__ images,
                          const float* __restrict__ boxes,
                          const float* __restrict__ patch,
                          float* __restrict__ ws) {
    const int bi = blockIdx.x;
    const int j_idx = blockIdx.y;
    const int z = blockIdx.z;
    const int b = bi >> 4, i = bi & 15;
    if (j_idx > i) return;

    __shared__ BoxGeo geo[NBOX];
    if (threadIdx.x < NBOX)
        geo[threadIdx.x] = make_geo(boxes + (b * NBOX + threadIdx.x) * 4);
    __syncthreads();

    const BoxGeo gi = geo[i];
    if (!gi.valid) return;              // solve_coeffs never reads these slots

    float* o = ws + WS_PAIR + (((size_t)(b * NBOX + i) * 17 + j_idx) * ZSPLIT + z) * 8;
    const int j = j_idx - 1;

    int ry0 = gi.y0, rx0 = gi.x0;
    int ry1 = gi.y0 + gi.ph, rx1 = gi.x0 + gi.pw;
    int jy0 = 0, jx0 = 0; float jphf = 1.f, jpwf = 1.f;
    if (j >= 0) {
        const BoxGeo gj = geo[j];
        if (!gj.valid) {
            if (threadIdx.x == 0) { for (int k = 0; k < 7; ++k) o[k] = 0.f; }
            return;
        }
        ry0 = max(ry0, gj.y0); rx0 = max(rx0, gj.x0);
        ry1 = min(ry1, gj.y0 + gj.ph); rx1 = min(rx1, gj.x0 + gj.pw);
        jy0 = gj.y0; jx0 = gj.x0;
        jphf = (float)gj.ph; jpwf = (float)gj.pw;
    }
    const int rw = rx1 - rx0, rh = ry1 - ry0;
    if (rw <= 0 || rh <= 0) {
        if (threadIdx.x == 0) { for (int k = 0; k < 7; ++k) o[k] = 0.f; }
        return;
    }
    const int n = rw * rh;
    const float* img = images + (size_t)b * IMG_H * IMG_W * 3;

    float v[7] = {0.f, 0.f, 0.f, 0.f, 0.f, 0.f, 0.f};
    for (int t = z * 256 + threadIdx.x; t < n; t += 256 * ZSPLIT) {
        const int y = ry0 + t / rw;
        const int x = rx0 + t % rw;
        bool inc = true;
        for (int k = j + 1; k < i; ++k) {
            const BoxGeo gk = geo[k];
            if (gk.valid && y >= gk.y0 && y < gk.y0 + gk.ph &&
                x >= gk.x0 && x < gk.x0 + gk.pw) { inc = false; break; }
        }
        if (inc) {
            float s[3];
            if (j >= 0) {
                bsample(patch, y - jy0, x - jx0, jphf, jpwf, s);
            } else {
                const float* p = img + ((size_t)y * IMG_W + x) * 3;
                s[0] = p[0]; s[1] = p[1]; s[2] = p[2];
            }
            v[0] += 1.f;
            v[1] += s[0]; v[2] += s[1]; v[3] += s[2];
            v[4] += s[0]*s[0]; v[5] += s[1]*s[1]; v[6] += s[2]*s[2];
        }
    }
    block_reduceN<7, 4>(v);
    if (threadIdx.x == 0) {
#pragma unroll
        for (int k = 0; k < 7; ++k) o[k] = v[k];
    }
}

// ---------------------------------------------------------------------------
// Kernel B: per-image 16-step recurrence. One wave per image.
// ---------------------------------------------------------------------------
__global__ void solve_coeffs(const float* __restrict__ boxes,
                             float* __restrict__ ws) {
    const int b = blockIdx.x;
    const int lane = threadIdx.x;       // 64 threads = 1 wave

    BoxGeo g = make_geo(boxes + (b * NBOX + (lane < NBOX ? lane : NBOX - 1)) * 4);
    float pm[3], ps[3];
#pragma unroll
    for (int c = 0; c < 3; ++c) { pm[c] = ws[WS_PMEAN + c]; ps[c] = ws[WS_PSTD + c]; }

    float sc[3] = {0.f, 0.f, 0.f}, of[3] = {0.f, 0.f, 0.f};

    for (int i = 0; i < NBOX; ++i) {
        const int valid_i = __shfl(g.valid, i, 64);
        if (!valid_i) continue;

        float cnt = 0.f, s1[3] = {0.f,0.f,0.f}, s2[3] = {0.f,0.f,0.f};
        if (lane <= i) {
            const float* p = ws + WS_PAIR +
                ((size_t)(b * NBOX + i) * 17 + lane) * ZSPLIT * 8;
#pragma unroll
            for (int zz = 0; zz < ZSPLIT; ++zz) {
                cnt   += p[zz*8 + 0];
                s1[0] += p[zz*8 + 1]; s1[1] += p[zz*8 + 2]; s1[2] += p[zz*8 + 3];
                s2[0] += p[zz*8 + 4]; s2[1] += p[zz*8 + 5]; s2[2] += p[zz*8 + 6];
            }
        }
        float ts[3], tq[3];
#pragma unroll
        for (int c = 0; c < 3; ++c) {
            if (lane == 0) { ts[c] = s1[c]; tq[c] = s2[c]; }
            else {
                ts[c] = sc[c] * s1[c] + of[c] * cnt;
                tq[c] = sc[c]*sc[c]*s2[c] + 2.f*sc[c]*of[c]*s1[c] + of[c]*of[c]*cnt;
            }
        }
#pragma unroll
        for (int c = 0; c < 3; ++c) {
#pragma unroll
            for (int off = 16; off > 0; off >>= 1) {
                ts[c] += __shfl_down(ts[c], off, 32);
                tq[c] += __shfl_down(tq[c], off, 32);
            }
        }
        const int phi = __shfl(g.ph, i, 64);
        const int pwi = __shfl(g.pw, i, 64);
        const float cntf = fmaxf((float)(phi * pwi), 1.0f);
        float nsc[3] = {0.f,0.f,0.f}, nof[3] = {0.f,0.f,0.f};
        if (lane == 0) {
#pragma unroll
            for (int c = 0; c < 3; ++c) {
                float mean = ts[c] / cntf;
                float var = tq[c] / cntf - mean * mean;
                float sd = sqrtf(fmaxf(var, 0.f)) + 1e-6f;
                nsc[c] = sd / ps[c];
                nof[c] = mean - pm[c] * nsc[c];
            }
        }
#pragma unroll
        for (int c = 0; c < 3; ++c) {
            float bs = __shfl(nsc[c], 0, 64);
            float bo = __shfl(nof[c], 0, 64);
            if (lane == i + 1) { sc[c] = bs; of[c] = bo; }
            if (lane == 0) {
                ws[WS_COEF + (size_t)(b * NBOX + i) * 8 + c] = bs;
                ws[WS_COEF + (size_t)(b * NBOX + i) * 8 + 3 + c] = bo;
            }
        }
    }
}

// ---------------------------------------------------------------------------
// Kernel C: render, 4 pixels (3 x float4) per thread.
// ---------------------------------------------------------------------------
__launch_bounds__(256)
__global__ void render(const float* __restrict__ images,
                       const float* __restrict__ boxes,
                       const float* __restrict__ patch,
                       const float* __restrict__ ws,
                       float* __restrict__ out) {
    const int b = blockIdx.y;
    __shared__ BoxGeo geo[NBOX];
    __shared__ float coef[NBOX][6];
    if (threadIdx.x < NBOX)
        geo[threadIdx.x] = make_geo(boxes + (b * NBOX + threadIdx.x) * 4);
    if (threadIdx.x < NBOX * 6) {
        int i = threadIdx.x / 6, c = threadIdx.x % 6;
        coef[i][c] = ws[WS_COEF + (size_t)(b * NBOX + i) * 8 + c];
    }
    __syncthreads();

    const int q = blockIdx.x * 256 + threadIdx.x;   // quad index 0..65535
    const int p0 = q << 2;
    const int y = p0 >> 9, x0 = p0 & 511;

    const float4* src = (const float4*)(images + (size_t)b * IMG_H * IMG_W * 3);
    float4* dst = (float4*)(out + (size_t)b * IMG_H * IMG_W * 3);

    float4 f[3];
    f[0] = src[3*q]; f[1] = src[3*q + 1]; f[2] = src[3*q + 2];
    float* r = (float*)f;

#pragma unroll
    for (int u = 0; u < 4; ++u) {
        const int x = x0 + u;
        int last = -1;
        for (int j = NBOX - 1; j >= 0; --j) {
            const BoxGeo g = geo[j];
            if (g.valid && y >= g.y0 && y < g.y0 + g.ph &&
                x >= g.x0 && x < g.x0 + g.pw) { last = j; break; }
        }
        if (last >= 0) {
            const BoxGeo g = geo[last];
            float s[3];
            bsample(patch, y - g.y0, x - g.x0, (float)g.ph, (float)g.pw, s);
            r[3*u + 0] = s[0] * coef[last][0] + coef[last][3];
            r[3*u + 1] = s[1] * coef[last][1] + coef[last][4];
            r[3*u + 2] = s[2] * coef[last][2] + coef[last][5];
        }
    }
    dst[3*q] = f[0]; dst[3*q + 1] = f[1]; dst[3*q + 2] = f[2];
}

extern "C" void kernel_launch(void* const* d_in, const int* in_sizes, int n_in,
                              void* d_out, int out_size, void* d_ws, size_t ws_size,
                              hipStream_t stream) {
    const float* images = (const float*)d_in[0];
    const float* boxes  = (const float*)d_in[1];
    const float* patch  = (const float*)d_in[2];
    float* out = (float*)d_out;
    float* ws  = (float*)d_ws;

    patch_stats_partial<<<RED_BLOCKS, 256, 0, stream>>>(patch, ws);
    patch_stats_final<<<1, RED_BLOCKS, 0, stream>>>(ws);
    pair_sums<<<dim3(NIMG * NBOX, 17, ZSPLIT), 256, 0, stream>>>(images, boxes, patch, ws);
    solve_coeffs<<<NIMG, 64, 0, stream>>>(boxes, ws);
    render<<<dim3(IMG_H * IMG_W / 4 / 256, NIMG), 256, 0, stream>>>(images, boxes, patch, ws, out);
}

// Round 9
// 100.763 us; speedup vs baseline: 2.2537x; 1.0523x over previous
//
#include <hip/hip_runtime.h>
#include <math.h>

#define IMG_H 512
#define IMG_W 512
#define PSIZE 512
#define NIMG 16
#define NBOX 16
#define RED_BLOCKS 256
#define ZSPLIT 4

// workspace layout (floats)
#define WS_PMEAN 0                                        // 3
#define WS_PSTD  3                                        // 3
#define WS_PART  6                                        // RED_BLOCKS*6
#define WS_PAIR  (6 + RED_BLOCKS * 6)                     // [b][i][j 0..16][z][8]
#define WS_COEF  (WS_PAIR + NIMG * NBOX * 17 * ZSPLIT * 8)// [b][i][8]

struct BoxGeo { int y0, x0, ph, pw, valid; };

__device__ __forceinline__ BoxGeo make_geo(const float* bx) {
    float ymin = bx[0], xmin = bx[1], ymax = bx[2], xmax = bx[3];
    float h = ymax - ymin, w = xmax - xmin;
    float pwf = h * 0.3f;            // SCALE
    float phf = 1.0f * pwf;          // ASPECT * pw
    float oy = ymin + h * 0.5f;
    float ox = xmin + w * 0.5f;
    float yp = fmaxf(oy - phf * 0.5f, 0.0f);
    float xp = fmaxf(ox - pwf * 0.5f, 0.0f);
    if (yp + phf > (float)IMG_H) yp = (float)IMG_H - phf;
    if (xp + pwf > (float)IMG_W) xp = (float)IMG_W - pwf;
    BoxGeo g;
    g.y0 = (int)yp; g.x0 = (int)xp;   // tf.cast truncation
    g.ph = (int)phf; g.pw = (int)pwf;
    g.valid = (phf > 60.0f) ? 1 : 0;  // MIN_PATCH_H tested on float ph
    return g;
}

__device__ __forceinline__ void bsample(const float* __restrict__ patch,
                                        int relY, int relX, float phf, float pwf,
                                        float s[3]) {
    float sy = ((float)relY + 0.5f) * (float)PSIZE / phf - 0.5f;
    sy = fminf(fmaxf(sy, 0.0f), (float)(PSIZE - 1));
    float sx = ((float)relX + 0.5f) * (float)PSIZE / pwf - 0.5f;
    sx = fminf(fmaxf(sx, 0.0f), (float)(PSIZE - 1));
    int y0 = (int)floorf(sy);
    int y1 = min(y0 + 1, PSIZE - 1);
    int x0 = (int)floorf(sx);
    int x1 = min(x0 + 1, PSIZE - 1);
    float wy = sy - (float)y0;
    float wx = sx - (float)x0;
    const float* p00 = patch + (y0 * PSIZE + x0) * 3;
    const float* p01 = patch + (y0 * PSIZE + x1) * 3;
    const float* p10 = patch + (y1 * PSIZE + x0) * 3;
    const float* p11 = patch + (y1 * PSIZE + x1) * 3;
#pragma unroll
    for (int c = 0; c < 3; ++c) {
        float top = (1.f - wx) * p00[c] + wx * p01[c];
        float bot = (1.f - wx) * p10[c] + wx * p11[c];
        s[c] = (1.f - wy) * top + wy * bot;
    }
}

template<int N, int NWAVES>
__device__ __forceinline__ void block_reduceN(float v[N]) {
    __shared__ float lds[NWAVES][N];
    const int lane = threadIdx.x & 63;
    const int wave = threadIdx.x >> 6;
    __syncthreads();
#pragma unroll
    for (int k = 0; k < N; ++k) {
#pragma unroll
        for (int off = 32; off > 0; off >>= 1)
            v[k] += __shfl_down(v[k], off, 64);
    }
    if (lane == 0) {
#pragma unroll
        for (int k = 0; k < N; ++k) lds[wave][k] = v[k];
    }
    __syncthreads();
    if (wave == 0) {
#pragma unroll
        for (int k = 0; k < N; ++k) {
            float x = (lane < NWAVES) ? lds[lane][k] : 0.0f;
#pragma unroll
            for (int off = 32; off > 0; off >>= 1)
                x += __shfl_down(x, off, 64);
            if (lane == 0) lds[0][k] = x;
        }
    }
    __syncthreads();
#pragma unroll
    for (int k = 0; k < N; ++k) v[k] = lds[0][k];
}

// ---------------------------------------------------------------------------
// patch mean/std — vectorized: thread g loads float4[3g..3g+2] = 4 RGB pixels
// ---------------------------------------------------------------------------
__global__ void patch_stats_partial(const float* __restrict__ patch,
                                    float* __restrict__ ws) {
    const int g = blockIdx.x * 256 + threadIdx.x;   // 0..65535
    const float4* p4 = (const float4*)patch;
    float4 a = p4[3 * g], b = p4[3 * g + 1], c = p4[3 * g + 2];
    // channels rotate: a=(R,G,B,R) b=(G,B,R,G) c=(B,R,G,B)
    float v[6];
    v[0] = a.x + a.w + b.z + c.y;
    v[1] = a.y + b.x + b.w + c.z;
    v[2] = a.z + b.y + c.x + c.w;
    v[3] = a.x*a.x + a.w*a.w + b.z*b.z + c.y*c.y;
    v[4] = a.y*a.y + b.x*b.x + b.w*b.w + c.z*c.z;
    v[5] = a.z*a.z + b.y*b.y + c.x*c.x + c.w*c.w;
    block_reduceN<6, 4>(v);
    if (threadIdx.x == 0) {
        float* o = ws + WS_PART + blockIdx.x * 6;
#pragma unroll
        for (int k = 0; k < 6; ++k) o[k] = v[k];
    }
}

__global__ void patch_stats_final(float* __restrict__ ws) {
    float v[6];
    const float* p = ws + WS_PART + threadIdx.x * 6;
#pragma unroll
    for (int k = 0; k < 6; ++k) v[k] = p[k];
    block_reduceN<6, 4>(v);
    if (threadIdx.x == 0) {
        const float n = (float)(PSIZE * PSIZE);
#pragma unroll
        for (int c = 0; c < 3; ++c) {
            float m = v[c] / n;
            float var = v[3 + c] / n - m * m;
            ws[WS_PMEAN + c] = m;
            ws[WS_PSTD + c] = sqrtf(fmaxf(var, 0.f)) + 1e-6f;
        }
    }
}

// ---------------------------------------------------------------------------
// Kernel A: pair sums over last-coverer regions.
// block = (b*16+i, j_idx 0..16, z). j = j_idx-1 (-1 = original image).
// For j>=0 scan only rect_i ∩ rect_j; z splits the pixel range 4-way.
// ---------------------------------------------------------------------------
__launch_bounds__(256)
__global__ void pair_sums(const float* __restrict__ images,
                          const float* __restrict__ boxes,
                          const float* __restrict__ patch,
                          float* __restrict__ ws) {
    const int bi = blockIdx.x;
    const int j_idx = blockIdx.y;
    const int z = blockIdx.z;
    const int b = bi >> 4, i = bi & 15;
    if (j_idx > i) return;

    __shared__ BoxGeo geo[NBOX];
    if (threadIdx.x < NBOX)
        geo[threadIdx.x] = make_geo(boxes + (b * NBOX + threadIdx.x) * 4);
    __syncthreads();

    const BoxGeo gi = geo[i];
    if (!gi.valid) return;              // solve_coeffs never reads these slots

    float* o = ws + WS_PAIR + (((size_t)(b * NBOX + i) * 17 + j_idx) * ZSPLIT + z) * 8;
    const int j = j_idx - 1;

    int ry0 = gi.y0, rx0 = gi.x0;
    int ry1 = gi.y0 + gi.ph, rx1 = gi.x0 + gi.pw;
    int jy0 = 0, jx0 = 0; float jphf = 1.f, jpwf = 1.f;
    if (j >= 0) {
        const BoxGeo gj = geo[j];
        if (!gj.valid) {
            if (threadIdx.x == 0) { for (int k = 0; k < 7; ++k) o[k] = 0.f; }
            return;
        }
        ry0 = max(ry0, gj.y0); rx0 = max(rx0, gj.x0);
        ry1 = min(ry1, gj.y0 + gj.ph); rx1 = min(rx1, gj.x0 + gj.pw);
        jy0 = gj.y0; jx0 = gj.x0;
        jphf = (float)gj.ph; jpwf = (float)gj.pw;
    }
    const int rw = rx1 - rx0, rh = ry1 - ry0;
    if (rw <= 0 || rh <= 0) {
        if (threadIdx.x == 0) { for (int k = 0; k < 7; ++k) o[k] = 0.f; }
        return;
    }
    const int n = rw * rh;
    const float* img = images + (size_t)b * IMG_H * IMG_W * 3;

    float v[7] = {0.f, 0.f, 0.f, 0.f, 0.f, 0.f, 0.f};
    for (int t = z * 256 + threadIdx.x; t < n; t += 256 * ZSPLIT) {
        const int y = ry0 + t / rw;
        const int x = rx0 + t % rw;
        bool inc = true;
        for (int k = j + 1; k < i; ++k) {
            const BoxGeo gk = geo[k];
            if (gk.valid && y >= gk.y0 && y < gk.y0 + gk.ph &&
                x >= gk.x0 && x < gk.x0 + gk.pw) { inc = false; break; }
        }
        if (inc) {
            float s[3];
            if (j >= 0) {
                bsample(patch, y - jy0, x - jx0, jphf, jpwf, s);
            } else {
                const float* p = img + ((size_t)y * IMG_W + x) * 3;
                s[0] = p[0]; s[1] = p[1]; s[2] = p[2];
            }
            v[0] += 1.f;
            v[1] += s[0]; v[2] += s[1]; v[3] += s[2];
            v[4] += s[0]*s[0]; v[5] += s[1]*s[1]; v[6] += s[2]*s[2];
        }
    }
    block_reduceN<7, 4>(v);
    if (threadIdx.x == 0) {
#pragma unroll
        for (int k = 0; k < 7; ++k) o[k] = v[k];
    }
}

// ---------------------------------------------------------------------------
// Kernel B: per-image 16-step recurrence. One wave per image.
// ---------------------------------------------------------------------------
__global__ void solve_coeffs(const float* __restrict__ boxes,
                             float* __restrict__ ws) {
    const int b = blockIdx.x;
    const int lane = threadIdx.x;       // 64 threads = 1 wave

    BoxGeo g = make_geo(boxes + (b * NBOX + (lane < NBOX ? lane : NBOX - 1)) * 4);
    float pm[3], ps[3];
#pragma unroll
    for (int c = 0; c < 3; ++c) { pm[c] = ws[WS_PMEAN + c]; ps[c] = ws[WS_PSTD + c]; }

    float sc[3] = {0.f, 0.f, 0.f}, of[3] = {0.f, 0.f, 0.f};

    for (int i = 0; i < NBOX; ++i) {
        const int valid_i = __shfl(g.valid, i, 64);
        if (!valid_i) continue;

        float cnt = 0.f, s1[3] = {0.f,0.f,0.f}, s2[3] = {0.f,0.f,0.f};
        if (lane <= i) {
            const float* p = ws + WS_PAIR +
                ((size_t)(b * NBOX + i) * 17 + lane) * ZSPLIT * 8;
#pragma unroll
            for (int zz = 0; zz < ZSPLIT; ++zz) {
                cnt   += p[zz*8 + 0];
                s1[0] += p[zz*8 + 1]; s1[1] += p[zz*8 + 2]; s1[2] += p[zz*8 + 3];
                s2[0] += p[zz*8 + 4]; s2[1] += p[zz*8 + 5]; s2[2] += p[zz*8 + 6];
            }
        }
        float ts[3], tq[3];
#pragma unroll
        for (int c = 0; c < 3; ++c) {
            if (lane == 0) { ts[c] = s1[c]; tq[c] = s2[c]; }
            else {
                ts[c] = sc[c] * s1[c] + of[c] * cnt;
                tq[c] = sc[c]*sc[c]*s2[c] + 2.f*sc[c]*of[c]*s1[c] + of[c]*of[c]*cnt;
            }
        }
#pragma unroll
        for (int c = 0; c < 3; ++c) {
#pragma unroll
            for (int off = 16; off > 0; off >>= 1) {
                ts[c] += __shfl_down(ts[c], off, 32);
                tq[c] += __shfl_down(tq[c], off, 32);
            }
        }
        const int phi = __shfl(g.ph, i, 64);
        const int pwi = __shfl(g.pw, i, 64);
        const float cntf = fmaxf((float)(phi * pwi), 1.0f);
        float nsc[3] = {0.f,0.f,0.f}, nof[3] = {0.f,0.f,0.f};
        if (lane == 0) {
#pragma unroll
            for (int c = 0; c < 3; ++c) {
                float mean = ts[c] / cntf;
                float var = tq[c] / cntf - mean * mean;
                float sd = sqrtf(fmaxf(var, 0.f)) + 1e-6f;
                nsc[c] = sd / ps[c];
                nof[c] = mean - pm[c] * nsc[c];
            }
        }
#pragma unroll
        for (int c = 0; c < 3; ++c) {
            float bs = __shfl(nsc[c], 0, 64);
            float bo = __shfl(nof[c], 0, 64);
            if (lane == i + 1) { sc[c] = bs; of[c] = bo; }
            if (lane == 0) {
                ws[WS_COEF + (size_t)(b * NBOX + i) * 8 + c] = bs;
                ws[WS_COEF + (size_t)(b * NBOX + i) * 8 + 3 + c] = bo;
            }
        }
    }
}

// ---------------------------------------------------------------------------
// Kernel C: render v2. Block = 2-row strip (1024 px, 4 px/thread).
// Shared 16-bit mask of boxes intersecting the strip -> fast copy path when 0,
// candidate-only last-coverer search otherwise.
// ---------------------------------------------------------------------------
__launch_bounds__(256)
__global__ void render(const float* __restrict__ images,
                       const float* __restrict__ boxes,
                       const float* __restrict__ patch,
                       const float* __restrict__ ws,
                       float* __restrict__ out) {
    const int b = blockIdx.y;
    const int tid = threadIdx.x;
    __shared__ BoxGeo geo[NBOX];
    __shared__ float coef[NBOX][6];
    __shared__ int smask;

    const int strip_y0 = blockIdx.x * 2;          // rows strip_y0, strip_y0+1

    if (tid == 0) smask = 0;
    if (tid < NBOX)
        geo[tid] = make_geo(boxes + (b * NBOX + tid) * 4);
    if (tid < NBOX * 6) {
        int i = tid / 6, c = tid % 6;
        coef[i][c] = ws[WS_COEF + (size_t)(b * NBOX + i) * 8 + c];
    }
    __syncthreads();
    if (tid < NBOX) {
        const BoxGeo g = geo[tid];
        if (g.valid && g.y0 < strip_y0 + 2 && g.y0 + g.ph > strip_y0)
            atomicOr(&smask, 1 << tid);
    }
    __syncthreads();

    const int q = blockIdx.x * 256 + tid;         // quad index
    const float4* src = (const float4*)(images + (size_t)b * IMG_H * IMG_W * 3);
    float4* dst = (float4*)(out + (size_t)b * IMG_H * IMG_W * 3);
    const int mask = smask;

    if (mask == 0) {                               // pure copy strip
        dst[3*q]     = src[3*q];
        dst[3*q + 1] = src[3*q + 1];
        dst[3*q + 2] = src[3*q + 2];
        return;
    }

    const int p0 = q << 2;
    const int y = p0 >> 9, x0 = p0 & 511;

    // find last (highest-index) coverer per pixel, candidates only
    int last[4];
    bool any_un = false;
#pragma unroll
    for (int u = 0; u < 4; ++u) {
        const int x = x0 + u;
        int lj = -1;
        int m = mask;
        while (m) {
            const int j = 31 - __clz(m);
            const BoxGeo g = geo[j];
            if (y >= g.y0 && y < g.y0 + g.ph && x >= g.x0 && x < g.x0 + g.pw) {
                lj = j; break;
            }
            m &= ~(1 << j);
        }
        last[u] = lj;
        any_un |= (lj < 0);
    }

    float4 f[3];
    if (any_un) { f[0] = src[3*q]; f[1] = src[3*q + 1]; f[2] = src[3*q + 2]; }
    float* r = (float*)f;

#pragma unroll
    for (int u = 0; u < 4; ++u) {
        if (last[u] >= 0) {
            const BoxGeo g = geo[last[u]];
            float s[3];
            bsample(patch, y - g.y0, (x0 + u) - g.x0, (float)g.ph, (float)g.pw, s);
            r[3*u + 0] = s[0] * coef[last[u]][0] + coef[last[u]][3];
            r[3*u + 1] = s[1] * coef[last[u]][1] + coef[last[u]][4];
            r[3*u + 2] = s[2] * coef[last[u]][2] + coef[last[u]][5];
        }
    }
    dst[3*q] = f[0]; dst[3*q + 1] = f[1]; dst[3*q + 2] = f[2];
}

extern "C" void kernel_launch(void* const* d_in, const int* in_sizes, int n_in,
                              void* d_out, int out_size, void* d_ws, size_t ws_size,
                              hipStream_t stream) {
    const float* images = (const float*)d_in[0];
    const float* boxes  = (const float*)d_in[1];
    const float* patch  = (const float*)d_in[2];
    float* out = (float*)d_out;
    float* ws  = (float*)d_ws;

    patch_stats_partial<<<RED_BLOCKS, 256, 0, stream>>>(patch, ws);
    patch_stats_final<<<1, RED_BLOCKS, 0, stream>>>(ws);
    pair_sums<<<dim3(NIMG * NBOX, 17, ZSPLIT), 256, 0, stream>>>(images, boxes, patch, ws);
    solve_coeffs<<<NIMG, 64, 0, stream>>>(boxes, ws);
    render<<<dim3(IMG_H * IMG_W / 4 / 256, NIMG), 256, 0, stream>>>(images, boxes, patch, ws, out);
}